// Round 7
// baseline (176.675 us; speedup 1.0000x reference)
//
#include <hip/hip_runtime.h>

#define HW    16384   // 128*128
#define Wh    128
#define Cin   64
#define C2    32
#define HW4   4096    // 64*64

typedef short short8 __attribute__((ext_vector_type(8)));     // 8 bf16 = 4 VGPRs
typedef float float4v __attribute__((ext_vector_type(4)));
typedef unsigned uint4v __attribute__((ext_vector_type(4)));

#define LOG2E 1.44269504f
#define OFFE  43.2808512f   // 30*log2(e): exp(s-30) == exp2(s*log2e - OFFE)

__device__ __forceinline__ unsigned pack2bf16(float lo, float hi) {
  unsigned ul = __builtin_bit_cast(unsigned, lo);
  unsigned uh = __builtin_bit_cast(unsigned, hi);
  ul = (ul + 0x7fffu + ((ul >> 16) & 1u)) >> 16;
  uh = (uh + 0x7fffu + ((uh >> 16) & 1u)) & 0xffff0000u;
  return ul | uh;
}
__device__ __forceinline__ unsigned short f2bf(float f) {
  unsigned u = __builtin_bit_cast(unsigned, f);
  return (unsigned short)((u + 0x7fffu + ((u >> 16) & 1u)) >> 16);
}
// RTZ-truncate two fp32 to bf16, lo in [15:0], hi in [31:16]
__device__ __forceinline__ unsigned packtrunc(float lo, float hi) {
  return __builtin_amdgcn_perm(__builtin_bit_cast(unsigned, hi),
                               __builtin_bit_cast(unsigned, lo), 0x07060302u);
}

// ---------------------------------------------------------------------------
// Kernel 0: weight repack. wAll[og][c][24] = {theta(8, x log2e), phi(8), g(8)}
// ---------------------------------------------------------------------------
__global__ __launch_bounds__(256) void repack_w_kern(
    const float* __restrict__ wt, const float* __restrict__ bt,
    const float* __restrict__ wp, const float* __restrict__ bp,
    const float* __restrict__ wg, const float* __restrict__ bg,
    float* __restrict__ wAll, float* __restrict__ bAll) {
  int idx = blockIdx.x * 256 + threadIdx.x;
  if (idx < 6144) {
    int og = idx / 1536, rem = idx % 1536;
    int c = rem / 24, j = rem % 24;
    int o = og * 8 + (j & 7);
    float v;
    if (j < 8)       v = wt[o * Cin + c] * LOG2E;
    else if (j < 16) v = wp[o * Cin + c];
    else             v = wg[o * Cin + c];
    wAll[idx] = v;
  } else if (idx < 6240) {
    int i2 = idx - 6144;
    int og = i2 / 24, j = i2 % 24;
    int o = og * 8 + (j & 7);
    bAll[i2] = (j < 8) ? bt[o] * LOG2E : (j < 16 ? bp[o] : bg[o]);
  }
}

// ---------------------------------------------------------------------------
// Kernel 1: FUSED theta+phi+g conv (+2x2 maxpool) — R19: NO LDS STAGING,
// NO MAIN-LOOP BARRIERS.
// R18 post-mortem: async global_load_lds staging was perfectly neutral ->
// staging latency was never the exposed cost; conv_qkv (inferred ~75 µs,
// hidden below attn in top-5) is 6-15x its roofline floors, so the
// remaining suspect is the LDS round-trip + 8 lockstep barriers + myPx
// permutation structure itself. This version deletes the whole class:
// thread tid owns full-res pixel pxbase+tid -> channel ch's loads
// x[ch*HW + pxbase + tid] are per-lane coalesced dwords; 64 independent
// loads/thread, zero barriers in the conv loop, waves desynchronized.
// Pooling permutation moved AFTER the conv: stash the 16 phi/g values in
// LDS once (stride 17 -> conflict-free writes), one barrier, wave 0
// reduces each pooled col with the EXACT same fmax tree as the old
// shfl_xor code: max(max(r0c0,r0c1), max(r1c0,r1c1)).
// Per-output arithmetic order unchanged (bias, then ch 0..63) ->
// bitwise-identical Q/K/V.
// ---------------------------------------------------------------------------
__global__ __launch_bounds__(256) void conv_qkv_kern(
    const float* __restrict__ x, const float* __restrict__ wAll,
    const float* __restrict__ bAll, unsigned short* __restrict__ Q,
    unsigned short* __restrict__ K, unsigned short* __restrict__ Vt) {
  __shared__ float smP[256][17];                 // phi/g pre-pool, 17.4 KB
  __shared__ unsigned short smV[8][64];          // 1 KB
  int tid = threadIdx.x;
  int og = blockIdx.y, bz = blockIdx.z;
  int pxbase = blockIdx.x * 2 * Wh;              // full-res rows 2i, 2i+1
  const float* xb = x + (size_t)bz * Cin * HW + pxbase + tid;
  const float* wc = wAll + og * 1536;            // uniform -> s_load
  const float* bb = bAll + og * 24;

  float acc[24];
#pragma unroll
  for (int k = 0; k < 24; ++k) acc[k] = bb[k];

#pragma unroll
  for (int ch = 0; ch < Cin; ++ch) {
    float xv = xb[(size_t)ch * HW];              // coalesced, no barrier
#pragma unroll
    for (int k = 0; k < 24; ++k)
      acc[k] = fmaf(wc[ch * 24 + k], xv, acc[k]);
  }

  int p = pxbase + tid;                          // global full-res pixel
  // theta -> Q
  {
    uint4 up;
    up.x = pack2bf16(acc[0], acc[1]); up.y = pack2bf16(acc[2], acc[3]);
    up.z = pack2bf16(acc[4], acc[5]); up.w = pack2bf16(acc[6], acc[7]);
    *(uint4*)(Q + ((size_t)bz * HW + p) * C2 + og * 8) = up;
  }
  // stash phi/g for pooling (writes: stride 17 odd -> 2 lanes/bank, free)
#pragma unroll
  for (int o = 0; o < 16; ++o) smP[tid][o] = acc[8 + o];
  __syncthreads();

  if (tid < 64) {                                // wave 0: one pooled col each
    int j = tid;
    float aP[8], aG[8];
#pragma unroll
    for (int o = 0; o < 8; ++o) {
      // exact replication of the old shfl_xor tree:
      // max(max(r0c0, r0c1), max(r1c0, r1c1))
      aP[o] = fmaxf(fmaxf(smP[2 * j][o],       smP[2 * j + 1][o]),
                    fmaxf(smP[128 + 2 * j][o], smP[129 + 2 * j][o]));
      aG[o] = fmaxf(fmaxf(smP[2 * j][8 + o],       smP[2 * j + 1][8 + o]),
                    fmaxf(smP[128 + 2 * j][8 + o], smP[129 + 2 * j][8 + o]));
    }
    int pp = blockIdx.x * 64 + j;                // global pooled pixel
    int loc = pp & 31, tile = pp >> 5;
    int prow = ((loc & 4) << 2) + ((loc >> 3) << 2) + (loc & 3);   // S^T perm
    uint4 up;
    up.x = pack2bf16(aP[0], aP[1]); up.y = pack2bf16(aP[2], aP[3]);
    up.z = pack2bf16(aP[4], aP[5]); up.w = pack2bf16(aP[6], aP[7]);
    *(uint4*)(K + ((size_t)bz * HW4 + tile * 32 + prow) * C2 + og * 8) = up;
#pragma unroll
    for (int o = 0; o < 8; ++o) smV[o][j] = f2bf(aG[o]);
  }
  __syncthreads();
  // coalesced V store: thread t -> channel t>>5, dword t&31 (2 keys)
  {
    int ch = tid >> 5, idx = tid & 31;
    unsigned v = ((unsigned*)smV)[ch * 32 + idx];
    *(unsigned*)(Vt + (size_t)bz * C2 * HW4 + (size_t)(og * 8 + ch) * HW4 +
                 blockIdx.x * 64 + 2 * idx) = v;
  }
}

// ---------------------------------------------------------------------------
// Kernel 2: MFMA flash attention + FUSED OUTPUT CONV (unchanged from R17).
// Main loop = EXACT R12 body (best measured); epilogue does merge+normalize
// in LDS then the 32->64 conv + bias + residual (conv_out folded in).
// ---------------------------------------------------------------------------
__global__ __launch_bounds__(256, 4) void attn_mfma_kern(
    const unsigned short* __restrict__ Qb, const unsigned short* __restrict__ Kb,
    const unsigned short* __restrict__ Vt, const float* __restrict__ x,
    const float* __restrict__ w_out, const float* __restrict__ b_out,
    float* __restrict__ out) {
  __shared__ float smY[3][64][33];   // 25.3 KB
  __shared__ float smL[4][64];       // 1 KB
  int lane = threadIdx.x & 63;
  int wv = threadIdx.x >> 6;
  int quad = lane >> 4, l16 = lane & 15;
  int bz = blockIdx.y;
  int qrow0 = blockIdx.x * 64;

  short8 qf[4];
#pragma unroll
  for (int f = 0; f < 4; ++f)
    qf[f] = *(const short8*)(Qb + ((size_t)bz * HW + qrow0 + f * 16 + l16) * C2 + quad * 8);
  const unsigned short* kb = Kb + ((size_t)bz * HW4 + wv * 1024) * C2;
  const unsigned short* vb = Vt + (size_t)bz * C2 * HW4 + wv * 1024;

  short8 ones;
#pragma unroll
  for (int i = 0; i < 8; ++i) ones[i] = (short)0x3F80;  // bf16 1.0

  float4v z = {0.f, 0.f, 0.f, 0.f};
  float4v ya[4] = {z, z, z, z};   // y cols l16 (ch 0..15)
  float4v yh[4] = {z, z, z, z};   // y cols 16+l16
  float4v y2[4] = {z, z, z, z};   // row sums l (ones-MFMA)
  float4v moff = {-OFFE, -OFFE, -OFFE, -OFFE};

  for (int t = 0; t < 32; ++t) {
    const unsigned short* kt = kb + (size_t)t * 32 * C2;
    const unsigned short* vt = vb + t * 32;
    short8 ka = *(const short8*)(kt + (size_t)l16 * C2 + quad * 8);
    short8 kh = *(const short8*)(kt + (size_t)(16 + l16) * C2 + quad * 8);
    short8 va = *(const short8*)(vt + (size_t)l16 * HW4 + quad * 8);
    short8 vh = *(const short8*)(vt + (size_t)(16 + l16) * HW4 + quad * 8);
#pragma unroll
    for (int f = 0; f < 4; ++f) {
      float4v sa = __builtin_amdgcn_mfma_f32_16x16x32_bf16(ka, qf[f], moff, 0, 0, 0);
      float4v sh = __builtin_amdgcn_mfma_f32_16x16x32_bf16(kh, qf[f], moff, 0, 0, 0);
      float e0 = __builtin_amdgcn_exp2f(sa[0]), e1 = __builtin_amdgcn_exp2f(sa[1]);
      float e2 = __builtin_amdgcn_exp2f(sa[2]), e3 = __builtin_amdgcn_exp2f(sa[3]);
      float g0 = __builtin_amdgcn_exp2f(sh[0]), g1 = __builtin_amdgcn_exp2f(sh[1]);
      float g2 = __builtin_amdgcn_exp2f(sh[2]), g3 = __builtin_amdgcn_exp2f(sh[3]);
      uint4v d = {packtrunc(e0, e1), packtrunc(e2, e3),
                  packtrunc(g0, g1), packtrunc(g2, g3)};
      short8 pf = __builtin_bit_cast(short8, d);
      ya[f] = __builtin_amdgcn_mfma_f32_16x16x32_bf16(pf, va,   ya[f], 0, 0, 0);
      yh[f] = __builtin_amdgcn_mfma_f32_16x16x32_bf16(pf, vh,   yh[f], 0, 0, 0);
      y2[f] = __builtin_amdgcn_mfma_f32_16x16x32_bf16(pf, ones, y2[f], 0, 0, 0);
    }
  }

  // merge the 4 key quarters
  if (l16 == 0) {
#pragma unroll
    for (int f = 0; f < 4; ++f)
#pragma unroll
      for (int r = 0; r < 4; ++r)
        smL[wv][f * 16 + quad * 4 + r] = y2[f][r];   // cols identical
  }
  if (wv > 0) {
    int pi = wv - 1;
#pragma unroll
    for (int f = 0; f < 4; ++f)
#pragma unroll
      for (int r = 0; r < 4; ++r) {
        int lr = f * 16 + quad * 4 + r;
        smY[pi][lr][l16] = ya[f][r];
        smY[pi][lr][16 + l16] = yh[f][r];
      }
  }
  __syncthreads();
  if (wv == 0) {
    // merge + normalize; final y-tile lands in smY[0] (each thread reads
    // then overwrites ONLY its own (row,col) slots -> no cross-thread hazard)
#pragma unroll
    for (int f = 0; f < 4; ++f)
#pragma unroll
      for (int r = 0; r < 4; ++r) {
        int lr = f * 16 + quad * 4 + r;
        float a0 = ya[f][r] + smY[0][lr][l16] + smY[1][lr][l16] + smY[2][lr][l16];
        float a1 = yh[f][r] + smY[0][lr][16 + l16] + smY[1][lr][16 + l16] + smY[2][lr][16 + l16];
        float L = smL[0][lr] + smL[1][lr] + smL[2][lr] + smL[3][lr];
        float inv = 1.f / L;
        smY[0][lr][l16] = a0 * inv;
        smY[0][lr][16 + l16] = a1 * inv;
      }
  }
  __syncthreads();

  // ---- fused output conv (32->64) + bias + residual (replaces conv_out) ----
  {
    int px = lane;                       // pixel within block 0..63
    float yv[C2];
#pragma unroll
    for (int c = 0; c < C2; ++c) yv[c] = smY[0][px][c];
    const float* xb = x + (size_t)bz * Cin * HW + qrow0 + px;
    float* ob = out + (size_t)bz * Cin * HW + qrow0 + px;
#pragma unroll
    for (int i = 0; i < 16; ++i) {
      int co = wv * 16 + i;              // wave-uniform -> w_out via s_load
      float s = b_out[co];
#pragma unroll
      for (int o = 0; o < C2; ++o) s = fmaf(w_out[co * C2 + o], yv[o], s);
      ob[(size_t)co * HW] = s + xb[(size_t)co * HW];
    }
  }
}

// ---------------------------------------------------------------------------
extern "C" void kernel_launch(void* const* d_in, const int* in_sizes, int n_in,
                              void* d_out, int out_size, void* d_ws, size_t ws_size,
                              hipStream_t stream) {
  const float* x       = (const float*)d_in[0];
  const float* w_theta = (const float*)d_in[1];
  const float* b_theta = (const float*)d_in[2];
  const float* w_phi   = (const float*)d_in[3];
  const float* b_phi   = (const float*)d_in[4];
  const float* w_g     = (const float*)d_in[5];
  const float* b_g     = (const float*)d_in[6];
  const float* w_out   = (const float*)d_in[7];
  const float* b_out   = (const float*)d_in[8];
  float* out = (float*)d_out;

  float* Yws = (float*)d_ws;                                   // (unused now)
  unsigned short* Qb = (unsigned short*)(Yws + (size_t)4 * HW * C2);
  unsigned short* Kb = Qb + (size_t)4 * HW * C2;
  unsigned short* Vt = Kb + (size_t)4 * HW4 * C2;
  float* wAll = (float*)(Vt + (size_t)4 * HW4 * C2);           // 6144 f
  float* bAll = wAll + 6144;                                   // 96 f

  repack_w_kern<<<25, 256, 0, stream>>>(w_theta, b_theta, w_phi, b_phi,
                                        w_g, b_g, wAll, bAll);
  conv_qkv_kern<<<dim3(64, 4, 4), 256, 0, stream>>>(x, wAll, bAll, Qb, Kb, Vt);
  attn_mfma_kern<<<dim3(HW / 64, 4), 256, 0, stream>>>(Qb, Kb, Vt, x,
                                                       w_out, b_out, out);
}

// Round 8
// 165.604 us; speedup vs baseline: 1.0669x; 1.0669x over previous
//
#include <hip/hip_runtime.h>

#define HW    16384   // 128*128
#define Wh    128
#define Cin   64
#define C2    32
#define HW4   4096    // 64*64

typedef short short8 __attribute__((ext_vector_type(8)));     // 8 bf16 = 4 VGPRs
typedef float float4v __attribute__((ext_vector_type(4)));
typedef unsigned uint4v __attribute__((ext_vector_type(4)));

#define LOG2E 1.44269504f
#define OFFE  43.2808512f   // 30*log2(e): exp(s-30) == exp2(s*log2e - OFFE)

__device__ __forceinline__ unsigned pack2bf16(float lo, float hi) {
  unsigned ul = __builtin_bit_cast(unsigned, lo);
  unsigned uh = __builtin_bit_cast(unsigned, hi);
  ul = (ul + 0x7fffu + ((ul >> 16) & 1u)) >> 16;
  uh = (uh + 0x7fffu + ((uh >> 16) & 1u)) & 0xffff0000u;
  return ul | uh;
}
__device__ __forceinline__ unsigned short f2bf(float f) {
  unsigned u = __builtin_bit_cast(unsigned, f);
  return (unsigned short)((u + 0x7fffu + ((u >> 16) & 1u)) >> 16);
}
// RTZ-truncate two fp32 to bf16, lo in [15:0], hi in [31:16]
__device__ __forceinline__ unsigned packtrunc(float lo, float hi) {
  return __builtin_amdgcn_perm(__builtin_bit_cast(unsigned, hi),
                               __builtin_bit_cast(unsigned, lo), 0x07060302u);
}

// ---------------------------------------------------------------------------
// Kernel 0: weight repack. wAll[og][c][24] = {theta(8, x log2e), phi(8), g(8)}
// ---------------------------------------------------------------------------
__global__ __launch_bounds__(256) void repack_w_kern(
    const float* __restrict__ wt, const float* __restrict__ bt,
    const float* __restrict__ wp, const float* __restrict__ bp,
    const float* __restrict__ wg, const float* __restrict__ bg,
    float* __restrict__ wAll, float* __restrict__ bAll) {
  int idx = blockIdx.x * 256 + threadIdx.x;
  if (idx < 6144) {
    int og = idx / 1536, rem = idx % 1536;
    int c = rem / 24, j = rem % 24;
    int o = og * 8 + (j & 7);
    float v;
    if (j < 8)       v = wt[o * Cin + c] * LOG2E;
    else if (j < 16) v = wp[o * Cin + c];
    else             v = wg[o * Cin + c];
    wAll[idx] = v;
  } else if (idx < 6240) {
    int i2 = idx - 6144;
    int og = i2 / 24, j = i2 % 24;
    int o = og * 8 + (j & 7);
    bAll[i2] = (j < 8) ? bt[o] * LOG2E : (j < 16 ? bp[o] : bg[o]);
  }
}

// ---------------------------------------------------------------------------
// Kernel 1: FUSED theta+phi+g conv (+2x2 maxpool) — EXACT R4/R0 version
// (LDS-staged, sync copies). R18 proved async staging neutral; R19 proved
// the barrier-free rewrite is 12 µs WORSE. This is the best-measured form.
// ---------------------------------------------------------------------------
__global__ __launch_bounds__(256) void conv_qkv_kern(
    const float* __restrict__ x, const float* __restrict__ wAll,
    const float* __restrict__ bAll, unsigned short* __restrict__ Q,
    unsigned short* __restrict__ K, unsigned short* __restrict__ Vt) {
  __shared__ float smX[2][8][256];               // 16 KB, double-buffered
  __shared__ unsigned short smV[8][64];          // 1 KB
  int tid = threadIdx.x;
  int og = blockIdx.y, bz = blockIdx.z;
  int pxbase = blockIdx.x * 2 * Wh;              // full-res rows 2i, 2i+1
  int jloc = tid >> 2;                           // pooled col 0..63
  int rpar = (tid >> 1) & 1, cpar = tid & 1;
  int myPx = rpar * Wh + 2 * jloc + cpar;        // local pixel 0..255
  const float* xb = x + (size_t)bz * Cin * HW + pxbase;
  const float* wc = wAll + og * 1536;            // uniform -> s_load
  const float* bb = bAll + og * 24;

  // stage chunk: 512 float4 = 256 threads x 2; ch = f>>6, p4 = f&63
  auto stage = [&](int cb8, int buf) {
#pragma unroll
    for (int u = 0; u < 2; ++u) {
      int f = u * 256 + tid;
      int ch = f >> 6, p4 = f & 63;
      *(float4*)&smX[buf][ch][p4 * 4] =
          *(const float4*)(xb + (size_t)(cb8 * 8 + ch) * HW + p4 * 4);
    }
  };

  float acc[24];
#pragma unroll
  for (int k = 0; k < 24; ++k) acc[k] = bb[k];

  stage(0, 0);
  __syncthreads();
  for (int cb8 = 0; cb8 < 8; ++cb8) {
    if (cb8 < 7) stage(cb8 + 1, (cb8 + 1) & 1);  // loads fly over compute
    float xv[8];
#pragma unroll
    for (int u = 0; u < 8; ++u) xv[u] = smX[cb8 & 1][u][myPx];
#pragma unroll
    for (int u = 0; u < 8; ++u) {
#pragma unroll
      for (int k = 0; k < 24; ++k)
        acc[k] = fmaf(wc[(cb8 * 8 + u) * 24 + k], xv[u], acc[k]);
    }
    __syncthreads();                             // staged buf ready for next
  }

  int pp = blockIdx.x * 64 + jloc;               // global pooled pixel
  int p = pxbase + myPx;                         // global full-res pixel
  // theta -> Q
  {
    uint4 up;
    up.x = pack2bf16(acc[0], acc[1]); up.y = pack2bf16(acc[2], acc[3]);
    up.z = pack2bf16(acc[4], acc[5]); up.w = pack2bf16(acc[6], acc[7]);
    *(uint4*)(Q + ((size_t)bz * HW + p) * C2 + og * 8) = up;
  }
  // 2x2 maxpool across lane-mates {4j..4j+3}
  float aP[8], aG[8];
#pragma unroll
  for (int o = 0; o < 8; ++o) {
    float vp = acc[8 + o], vg = acc[16 + o];
    vp = fmaxf(vp, __shfl_xor(vp, 1)); vp = fmaxf(vp, __shfl_xor(vp, 2));
    vg = fmaxf(vg, __shfl_xor(vg, 1)); vg = fmaxf(vg, __shfl_xor(vg, 2));
    aP[o] = vp; aG[o] = vg;
  }
  if ((tid & 3) == 0) {
    int loc = pp & 31, tile = pp >> 5;
    int prow = ((loc & 4) << 2) + ((loc >> 3) << 2) + (loc & 3);   // S^T perm
    uint4 up;
    up.x = pack2bf16(aP[0], aP[1]); up.y = pack2bf16(aP[2], aP[3]);
    up.z = pack2bf16(aP[4], aP[5]); up.w = pack2bf16(aP[6], aP[7]);
    *(uint4*)(K + ((size_t)bz * HW4 + tile * 32 + prow) * C2 + og * 8) = up;
#pragma unroll
    for (int o = 0; o < 8; ++o) smV[o][tid >> 2] = f2bf(aG[o]);
  }
  __syncthreads();
  // coalesced V store: thread t -> channel t>>5, dword t&31 (2 keys)
  {
    int ch = tid >> 5, idx = tid & 31;
    unsigned v = ((unsigned*)smV)[ch * 32 + idx];
    *(unsigned*)(Vt + (size_t)bz * C2 * HW4 + (size_t)(og * 8 + ch) * HW4 +
                 blockIdx.x * 64 + 2 * idx) = v;
  }
}

// ---------------------------------------------------------------------------
// Kernel 2: MFMA flash attention — R21: standalone again (R5's conv_out
// fusion was a NET LOSS: +16.3 µs on attn to save 12.7 -> reverted to the
// R4/R12 form, best measured 60.8) + K/V load issue PINNED with
// sched_barrier(0). R16's prefetch was neutral because the compiler re-sank
// the loads (VGPR fell to 60 = register-minimized schedule). The fence
// constrains ONLY load-issue position — the f-loop's proven depth-first
// compute schedule is untouched (R13's regression came from reordering
// compute, not loads). Loads now sit ~450 issue-cyc ahead of first use;
// compiler emits counted vmcnt for va/vh.
// Tripwire: WRITE_SIZE >> 8.2 MB = spill -> drop the pin next round.
// ---------------------------------------------------------------------------
__global__ __launch_bounds__(256, 4) void attn_mfma_kern(
    const unsigned short* __restrict__ Qb, const unsigned short* __restrict__ Kb,
    const unsigned short* __restrict__ Vt, float* __restrict__ Y) {
  __shared__ float smY[3][64][33];   // 25.3 KB
  __shared__ float smL[4][64];       // 1 KB
  int lane = threadIdx.x & 63;
  int wv = threadIdx.x >> 6;
  int quad = lane >> 4, l16 = lane & 15;
  int bz = blockIdx.y;
  int qrow0 = blockIdx.x * 64;

  short8 qf[4];
#pragma unroll
  for (int f = 0; f < 4; ++f)
    qf[f] = *(const short8*)(Qb + ((size_t)bz * HW + qrow0 + f * 16 + l16) * C2 + quad * 8);
  const unsigned short* kb = Kb + ((size_t)bz * HW4 + wv * 1024) * C2;
  const unsigned short* vb = Vt + (size_t)bz * C2 * HW4 + wv * 1024;

  short8 ones;
#pragma unroll
  for (int i = 0; i < 8; ++i) ones[i] = (short)0x3F80;  // bf16 1.0

  float4v z = {0.f, 0.f, 0.f, 0.f};
  float4v ya[4] = {z, z, z, z};   // y cols l16 (ch 0..15)
  float4v yh[4] = {z, z, z, z};   // y cols 16+l16
  float4v y2[4] = {z, z, z, z};   // row sums l (ones-MFMA)
  float4v moff = {-OFFE, -OFFE, -OFFE, -OFFE};

  // prefetch K tile 0 into registers
  short8 ka = *(const short8*)(kb + (size_t)l16 * C2 + quad * 8);
  short8 kh = *(const short8*)(kb + (size_t)(16 + l16) * C2 + quad * 8);

  for (int t = 0; t < 32; ++t) {
    // V(t) + K(t+1): issue all 4 loads NOW, pin them above the compute
    const unsigned short* vt = vb + t * 32;
    short8 va = *(const short8*)(vt + (size_t)l16 * HW4 + quad * 8);
    short8 vh = *(const short8*)(vt + (size_t)(16 + l16) * HW4 + quad * 8);
    int tn = (t + 1) & 31;                       // t=31 wraps: harmless reload
    const unsigned short* ktn = kb + (size_t)tn * 32 * C2;
    short8 nka = *(const short8*)(ktn + (size_t)l16 * C2 + quad * 8);
    short8 nkh = *(const short8*)(ktn + (size_t)(16 + l16) * C2 + quad * 8);
    __builtin_amdgcn_sched_barrier(0);           // loads stay issued HERE

    // depth-first per-fragment body — EXACT R12 form (proven best schedule)
#pragma unroll
    for (int f = 0; f < 4; ++f) {
      float4v sa = __builtin_amdgcn_mfma_f32_16x16x32_bf16(ka, qf[f], moff, 0, 0, 0);
      float4v sh = __builtin_amdgcn_mfma_f32_16x16x32_bf16(kh, qf[f], moff, 0, 0, 0);
      float e0 = __builtin_amdgcn_exp2f(sa[0]), e1 = __builtin_amdgcn_exp2f(sa[1]);
      float e2 = __builtin_amdgcn_exp2f(sa[2]), e3 = __builtin_amdgcn_exp2f(sa[3]);
      float g0 = __builtin_amdgcn_exp2f(sh[0]), g1 = __builtin_amdgcn_exp2f(sh[1]);
      float g2 = __builtin_amdgcn_exp2f(sh[2]), g3 = __builtin_amdgcn_exp2f(sh[3]);
      uint4v d = {packtrunc(e0, e1), packtrunc(e2, e3),
                  packtrunc(g0, g1), packtrunc(g2, g3)};
      short8 pf = __builtin_bit_cast(short8, d);
      ya[f] = __builtin_amdgcn_mfma_f32_16x16x32_bf16(pf, va,   ya[f], 0, 0, 0);
      yh[f] = __builtin_amdgcn_mfma_f32_16x16x32_bf16(pf, vh,   yh[f], 0, 0, 0);
      y2[f] = __builtin_amdgcn_mfma_f32_16x16x32_bf16(pf, ones, y2[f], 0, 0, 0);
    }

    ka = nka; kh = nkh;
  }

  // merge the 4 key quarters (R12 epilogue, unchanged)
  if (l16 == 0) {
#pragma unroll
    for (int f = 0; f < 4; ++f)
#pragma unroll
      for (int r = 0; r < 4; ++r)
        smL[wv][f * 16 + quad * 4 + r] = y2[f][r];   // cols identical
  }
  if (wv > 0) {
    int pi = wv - 1;
#pragma unroll
    for (int f = 0; f < 4; ++f)
#pragma unroll
      for (int r = 0; r < 4; ++r) {
        int lr = f * 16 + quad * 4 + r;
        smY[pi][lr][l16] = ya[f][r];
        smY[pi][lr][16 + l16] = yh[f][r];
      }
  }
  __syncthreads();
  if (wv == 0) {
#pragma unroll
    for (int f = 0; f < 4; ++f)
#pragma unroll
      for (int r = 0; r < 4; ++r) {
        int lr = f * 16 + quad * 4 + r;
        float a0 = ya[f][r] + smY[0][lr][l16] + smY[1][lr][l16] + smY[2][lr][l16];
        float a1 = yh[f][r] + smY[0][lr][16 + l16] + smY[1][lr][16 + l16] + smY[2][lr][16 + l16];
        float L = smL[0][lr] + smL[1][lr] + smL[2][lr] + smL[3][lr];
        float inv = 1.f / L;
        size_t rw = (size_t)bz * HW + qrow0 + lr;
        Y[rw * C2 + l16] = a0 * inv;
        Y[rw * C2 + 16 + l16] = a1 * inv;
      }
  }
}

// ---------------------------------------------------------------------------
// Kernel 3: output conv (32->64) + bias + residual — R21: LDS-STAGED Y READ.
// Old version read y as 8 float4s with consecutive lanes 128 B apart: 64 L2
// requests/instr (8x amplification). Now: the block's Y segment (256 px x 32
// ch = 32 KB, CONTIGUOUS) is staged via coalesced float4 loads, read back at
// stride-33 rows (lane t & t+32 share a bank = 2/bank = free). cog split
// 8->4 (16 ch/block): grid (64,4,4)=1024 blocks x 33.8 KB LDS = exactly
// 4 blocks/CU. FMA order unchanged (bias, then o ascending) -> bitwise-
// identical output.
// ---------------------------------------------------------------------------
__global__ __launch_bounds__(256) void conv_out_kern(
    const float* __restrict__ Y, const float* __restrict__ x,
    const float* __restrict__ w, const float* __restrict__ bias,
    float* __restrict__ out) {
  __shared__ float smY[256][33];             // 33.8 KB
  int tid = threadIdx.x;
  int p0 = blockIdx.x * 256;
  int cog = blockIdx.y, bz = blockIdx.z;     // cog 0..3 -> channels cog*16..+15
  const float4* Yseg = (const float4*)(Y + ((size_t)bz * HW + p0) * C2);
#pragma unroll
  for (int u = 0; u < 8; ++u) {              // coalesced: 1 KB/instr/wave
    int f = u * 256 + tid;
    float4 v = Yseg[f];
    int px = f >> 3, c4 = (f & 7) * 4;
    smY[px][c4] = v.x; smY[px][c4 + 1] = v.y;
    smY[px][c4 + 2] = v.z; smY[px][c4 + 3] = v.w;
  }
  int p = p0 + tid;
  const float* xb = x + (size_t)bz * Cin * HW + p;
  float xr[16];
#pragma unroll
  for (int i = 0; i < 16; ++i)               // residual loads in flight
    xr[i] = xb[(size_t)(cog * 16 + i) * HW];
  __syncthreads();
  float y[C2];
#pragma unroll
  for (int o = 0; o < C2; ++o) y[o] = smY[tid][o];
  float* ob = out + (size_t)bz * Cin * HW + p;
#pragma unroll
  for (int i = 0; i < 16; ++i) {
    int co = cog * 16 + i;
    float s = bias[co];
#pragma unroll
    for (int o = 0; o < C2; ++o) s = fmaf(w[co * C2 + o], y[o], s);  // s_load
    ob[(size_t)co * HW] = s + xr[i];
  }
}

// ---------------------------------------------------------------------------
extern "C" void kernel_launch(void* const* d_in, const int* in_sizes, int n_in,
                              void* d_out, int out_size, void* d_ws, size_t ws_size,
                              hipStream_t stream) {
  const float* x       = (const float*)d_in[0];
  const float* w_theta = (const float*)d_in[1];
  const float* b_theta = (const float*)d_in[2];
  const float* w_phi   = (const float*)d_in[3];
  const float* b_phi   = (const float*)d_in[4];
  const float* w_g     = (const float*)d_in[5];
  const float* b_g     = (const float*)d_in[6];
  const float* w_out   = (const float*)d_in[7];
  const float* b_out   = (const float*)d_in[8];
  float* out = (float*)d_out;

  float* Yws = (float*)d_ws;                                   // 8 MB fp32
  unsigned short* Qb = (unsigned short*)(Yws + (size_t)4 * HW * C2);
  unsigned short* Kb = Qb + (size_t)4 * HW * C2;
  unsigned short* Vt = Kb + (size_t)4 * HW4 * C2;
  float* wAll = (float*)(Vt + (size_t)4 * HW4 * C2);           // 6144 f
  float* bAll = wAll + 6144;                                   // 96 f

  repack_w_kern<<<25, 256, 0, stream>>>(w_theta, b_theta, w_phi, b_phi,
                                        w_g, b_g, wAll, bAll);
  conv_qkv_kern<<<dim3(64, 4, 4), 256, 0, stream>>>(x, wAll, bAll, Qb, Kb, Vt);
  attn_mfma_kern<<<dim3(HW / 64, 4), 256, 0, stream>>>(Qb, Kb, Vt, Yws);
  conv_out_kern<<<dim3(64, 4, 4), 256, 0, stream>>>(Yws, x, w_out, b_out, out);
}

// Round 9
// 161.057 us; speedup vs baseline: 1.0970x; 1.0282x over previous
//
#include <hip/hip_runtime.h>

#define HW    16384   // 128*128
#define Wh    128
#define Cin   64
#define C2    32
#define HW4   4096    // 64*64

typedef short short8 __attribute__((ext_vector_type(8)));     // 8 bf16 = 4 VGPRs
typedef float float4v __attribute__((ext_vector_type(4)));
typedef unsigned uint4v __attribute__((ext_vector_type(4)));

#define LOG2E 1.44269504f
#define OFFE  43.2808512f   // 30*log2(e): exp(s-30) == exp2(s*log2e - OFFE)

__device__ __forceinline__ unsigned pack2bf16(float lo, float hi) {
  unsigned ul = __builtin_bit_cast(unsigned, lo);
  unsigned uh = __builtin_bit_cast(unsigned, hi);
  ul = (ul + 0x7fffu + ((ul >> 16) & 1u)) >> 16;
  uh = (uh + 0x7fffu + ((uh >> 16) & 1u)) & 0xffff0000u;
  return ul | uh;
}
__device__ __forceinline__ unsigned short f2bf(float f) {
  unsigned u = __builtin_bit_cast(unsigned, f);
  return (unsigned short)((u + 0x7fffu + ((u >> 16) & 1u)) >> 16);
}
// RTZ-truncate two fp32 to bf16, lo in [15:0], hi in [31:16]
__device__ __forceinline__ unsigned packtrunc(float lo, float hi) {
  return __builtin_amdgcn_perm(__builtin_bit_cast(unsigned, hi),
                               __builtin_bit_cast(unsigned, lo), 0x07060302u);
}

// ---------------------------------------------------------------------------
// Kernel 0: weight repack. wAll[og][c][24] = {theta(8, x log2e), phi(8), g(8)}
// ---------------------------------------------------------------------------
__global__ __launch_bounds__(256) void repack_w_kern(
    const float* __restrict__ wt, const float* __restrict__ bt,
    const float* __restrict__ wp, const float* __restrict__ bp,
    const float* __restrict__ wg, const float* __restrict__ bg,
    float* __restrict__ wAll, float* __restrict__ bAll) {
  int idx = blockIdx.x * 256 + threadIdx.x;
  if (idx < 6144) {
    int og = idx / 1536, rem = idx % 1536;
    int c = rem / 24, j = rem % 24;
    int o = og * 8 + (j & 7);
    float v;
    if (j < 8)       v = wt[o * Cin + c] * LOG2E;
    else if (j < 16) v = wp[o * Cin + c];
    else             v = wg[o * Cin + c];
    wAll[idx] = v;
  } else if (idx < 6240) {
    int i2 = idx - 6144;
    int og = i2 / 24, j = i2 % 24;
    int o = og * 8 + (j & 7);
    bAll[i2] = (j < 8) ? bt[o] * LOG2E : (j < 16 ? bp[o] : bg[o]);
  }
}

// ---------------------------------------------------------------------------
// Kernel 1: FUSED theta+phi+g conv (+2x2 maxpool) — EXACT R4/R0 version
// (best measured; R18 async neutral, R19 rewrite -12 µs).
// ---------------------------------------------------------------------------
__global__ __launch_bounds__(256) void conv_qkv_kern(
    const float* __restrict__ x, const float* __restrict__ wAll,
    const float* __restrict__ bAll, unsigned short* __restrict__ Q,
    unsigned short* __restrict__ K, unsigned short* __restrict__ Vt) {
  __shared__ float smX[2][8][256];               // 16 KB, double-buffered
  __shared__ unsigned short smV[8][64];          // 1 KB
  int tid = threadIdx.x;
  int og = blockIdx.y, bz = blockIdx.z;
  int pxbase = blockIdx.x * 2 * Wh;              // full-res rows 2i, 2i+1
  int jloc = tid >> 2;                           // pooled col 0..63
  int rpar = (tid >> 1) & 1, cpar = tid & 1;
  int myPx = rpar * Wh + 2 * jloc + cpar;        // local pixel 0..255
  const float* xb = x + (size_t)bz * Cin * HW + pxbase;
  const float* wc = wAll + og * 1536;            // uniform -> s_load
  const float* bb = bAll + og * 24;

  // stage chunk: 512 float4 = 256 threads x 2; ch = f>>6, p4 = f&63
  auto stage = [&](int cb8, int buf) {
#pragma unroll
    for (int u = 0; u < 2; ++u) {
      int f = u * 256 + tid;
      int ch = f >> 6, p4 = f & 63;
      *(float4*)&smX[buf][ch][p4 * 4] =
          *(const float4*)(xb + (size_t)(cb8 * 8 + ch) * HW + p4 * 4);
    }
  };

  float acc[24];
#pragma unroll
  for (int k = 0; k < 24; ++k) acc[k] = bb[k];

  stage(0, 0);
  __syncthreads();
  for (int cb8 = 0; cb8 < 8; ++cb8) {
    if (cb8 < 7) stage(cb8 + 1, (cb8 + 1) & 1);  // loads fly over compute
    float xv[8];
#pragma unroll
    for (int u = 0; u < 8; ++u) xv[u] = smX[cb8 & 1][u][myPx];
#pragma unroll
    for (int u = 0; u < 8; ++u) {
#pragma unroll
      for (int k = 0; k < 24; ++k)
        acc[k] = fmaf(wc[(cb8 * 8 + u) * 24 + k], xv[u], acc[k]);
    }
    __syncthreads();                             // staged buf ready for next
  }

  int pp = blockIdx.x * 64 + jloc;               // global pooled pixel
  int p = pxbase + myPx;                         // global full-res pixel
  // theta -> Q
  {
    uint4 up;
    up.x = pack2bf16(acc[0], acc[1]); up.y = pack2bf16(acc[2], acc[3]);
    up.z = pack2bf16(acc[4], acc[5]); up.w = pack2bf16(acc[6], acc[7]);
    *(uint4*)(Q + ((size_t)bz * HW + p) * C2 + og * 8) = up;
  }
  // 2x2 maxpool across lane-mates {4j..4j+3}
  float aP[8], aG[8];
#pragma unroll
  for (int o = 0; o < 8; ++o) {
    float vp = acc[8 + o], vg = acc[16 + o];
    vp = fmaxf(vp, __shfl_xor(vp, 1)); vp = fmaxf(vp, __shfl_xor(vp, 2));
    vg = fmaxf(vg, __shfl_xor(vg, 1)); vg = fmaxf(vg, __shfl_xor(vg, 2));
    aP[o] = vp; aG[o] = vg;
  }
  if ((tid & 3) == 0) {
    int loc = pp & 31, tile = pp >> 5;
    int prow = ((loc & 4) << 2) + ((loc >> 3) << 2) + (loc & 3);   // S^T perm
    uint4 up;
    up.x = pack2bf16(aP[0], aP[1]); up.y = pack2bf16(aP[2], aP[3]);
    up.z = pack2bf16(aP[4], aP[5]); up.w = pack2bf16(aP[6], aP[7]);
    *(uint4*)(K + ((size_t)bz * HW4 + tile * 32 + prow) * C2 + og * 8) = up;
#pragma unroll
    for (int o = 0; o < 8; ++o) smV[o][tid >> 2] = f2bf(aG[o]);
  }
  __syncthreads();
  // coalesced V store: thread t -> channel t>>5, dword t&31 (2 keys)
  {
    int ch = tid >> 5, idx = tid & 31;
    unsigned v = ((unsigned*)smV)[ch * 32 + idx];
    *(unsigned*)(Vt + (size_t)bz * C2 * HW4 + (size_t)(og * 8 + ch) * HW4 +
                 blockIdx.x * 64 + 2 * idx) = v;
  }
}

// ---------------------------------------------------------------------------
// Kernel 2: MFMA flash attention — R22: TWO 32-KEY TILES PER ITERATION.
// Ledger finding: wall/iter is ~CONSTANT vs chains/iter (R15: 2 chains ->
// ~4.1k cyc/iter; R12: 4 chains -> ~4.4k) => fixed cost ~3.8k cyc/iter
// (K/V load + waitcnt + loop-carried pattern), marginal chain ~150 cyc.
// R15's 2x slowdown = paying the fixed cost twice as often. So go DENSER:
// KVBLK=64 (tiles 2t, 2t+1) per iteration -> 16 iters: predicted
// 16 x (3.8k + 8x150) ~= 80k cyc ~= 33 µs vs 59-61 now.
// Accumulation order per acc[f] unchanged (tile 2t then 2t+1 = sequence
// 0..31 as before) -> bitwise-identical. +16 VGPR for 2nd tile's K/V
// (~80-100 < 128 cap at (256,4)). Chain code = exact R12 depth-first form
// (5 scheduling probes proved: leave the compiler's schedule alone).
// Tripwire: WRITE_SIZE >> 8.2 MB = spill -> revert to R12 exact.
// ---------------------------------------------------------------------------
__global__ __launch_bounds__(256, 4) void attn_mfma_kern(
    const unsigned short* __restrict__ Qb, const unsigned short* __restrict__ Kb,
    const unsigned short* __restrict__ Vt, float* __restrict__ Y) {
  __shared__ float smY[3][64][33];   // 25.3 KB
  __shared__ float smL[4][64];       // 1 KB
  int lane = threadIdx.x & 63;
  int wv = threadIdx.x >> 6;
  int quad = lane >> 4, l16 = lane & 15;
  int bz = blockIdx.y;
  int qrow0 = blockIdx.x * 64;

  short8 qf[4];
#pragma unroll
  for (int f = 0; f < 4; ++f)
    qf[f] = *(const short8*)(Qb + ((size_t)bz * HW + qrow0 + f * 16 + l16) * C2 + quad * 8);
  const unsigned short* kb = Kb + ((size_t)bz * HW4 + wv * 1024) * C2;
  const unsigned short* vb = Vt + (size_t)bz * C2 * HW4 + wv * 1024;

  short8 ones;
#pragma unroll
  for (int i = 0; i < 8; ++i) ones[i] = (short)0x3F80;  // bf16 1.0

  float4v z = {0.f, 0.f, 0.f, 0.f};
  float4v ya[4] = {z, z, z, z};   // y cols l16 (ch 0..15)
  float4v yh[4] = {z, z, z, z};   // y cols 16+l16
  float4v y2[4] = {z, z, z, z};   // row sums l (ones-MFMA)
  float4v moff = {-OFFE, -OFFE, -OFFE, -OFFE};

  for (int t = 0; t < 16; ++t) {
    // tile pair 2t, 2t+1: all 8 loads issued at iteration top
    const unsigned short* kt0 = kb + (size_t)(2 * t) * 32 * C2;
    const unsigned short* vt0 = vb + (2 * t) * 32;
    short8 ka0 = *(const short8*)(kt0 + (size_t)l16 * C2 + quad * 8);
    short8 kh0 = *(const short8*)(kt0 + (size_t)(16 + l16) * C2 + quad * 8);
    short8 va0 = *(const short8*)(vt0 + (size_t)l16 * HW4 + quad * 8);
    short8 vh0 = *(const short8*)(vt0 + (size_t)(16 + l16) * HW4 + quad * 8);
    const unsigned short* kt1 = kt0 + (size_t)32 * C2;
    const unsigned short* vt1 = vt0 + 32;
    short8 ka1 = *(const short8*)(kt1 + (size_t)l16 * C2 + quad * 8);
    short8 kh1 = *(const short8*)(kt1 + (size_t)(16 + l16) * C2 + quad * 8);
    short8 va1 = *(const short8*)(vt1 + (size_t)l16 * HW4 + quad * 8);
    short8 vh1 = *(const short8*)(vt1 + (size_t)(16 + l16) * HW4 + quad * 8);
#pragma unroll
    for (int f = 0; f < 4; ++f) {
      // ---- tile 2t (exact R12 chain) ----
      {
        float4v sa = __builtin_amdgcn_mfma_f32_16x16x32_bf16(ka0, qf[f], moff, 0, 0, 0);
        float4v sh = __builtin_amdgcn_mfma_f32_16x16x32_bf16(kh0, qf[f], moff, 0, 0, 0);
        float e0 = __builtin_amdgcn_exp2f(sa[0]), e1 = __builtin_amdgcn_exp2f(sa[1]);
        float e2 = __builtin_amdgcn_exp2f(sa[2]), e3 = __builtin_amdgcn_exp2f(sa[3]);
        float g0 = __builtin_amdgcn_exp2f(sh[0]), g1 = __builtin_amdgcn_exp2f(sh[1]);
        float g2 = __builtin_amdgcn_exp2f(sh[2]), g3 = __builtin_amdgcn_exp2f(sh[3]);
        uint4v d = {packtrunc(e0, e1), packtrunc(e2, e3),
                    packtrunc(g0, g1), packtrunc(g2, g3)};
        short8 pf = __builtin_bit_cast(short8, d);
        ya[f] = __builtin_amdgcn_mfma_f32_16x16x32_bf16(pf, va0,  ya[f], 0, 0, 0);
        yh[f] = __builtin_amdgcn_mfma_f32_16x16x32_bf16(pf, vh0,  yh[f], 0, 0, 0);
        y2[f] = __builtin_amdgcn_mfma_f32_16x16x32_bf16(pf, ones, y2[f], 0, 0, 0);
      }
      // ---- tile 2t+1 (same chain, second half of the pair) ----
      {
        float4v sa = __builtin_amdgcn_mfma_f32_16x16x32_bf16(ka1, qf[f], moff, 0, 0, 0);
        float4v sh = __builtin_amdgcn_mfma_f32_16x16x32_bf16(kh1, qf[f], moff, 0, 0, 0);
        float e0 = __builtin_amdgcn_exp2f(sa[0]), e1 = __builtin_amdgcn_exp2f(sa[1]);
        float e2 = __builtin_amdgcn_exp2f(sa[2]), e3 = __builtin_amdgcn_exp2f(sa[3]);
        float g0 = __builtin_amdgcn_exp2f(sh[0]), g1 = __builtin_amdgcn_exp2f(sh[1]);
        float g2 = __builtin_amdgcn_exp2f(sh[2]), g3 = __builtin_amdgcn_exp2f(sh[3]);
        uint4v d = {packtrunc(e0, e1), packtrunc(e2, e3),
                    packtrunc(g0, g1), packtrunc(g2, g3)};
        short8 pf = __builtin_bit_cast(short8, d);
        ya[f] = __builtin_amdgcn_mfma_f32_16x16x32_bf16(pf, va1,  ya[f], 0, 0, 0);
        yh[f] = __builtin_amdgcn_mfma_f32_16x16x32_bf16(pf, vh1,  yh[f], 0, 0, 0);
        y2[f] = __builtin_amdgcn_mfma_f32_16x16x32_bf16(pf, ones, y2[f], 0, 0, 0);
      }
    }
  }

  // merge the 4 key quarters (R12 epilogue, unchanged)
  if (l16 == 0) {
#pragma unroll
    for (int f = 0; f < 4; ++f)
#pragma unroll
      for (int r = 0; r < 4; ++r)
        smL[wv][f * 16 + quad * 4 + r] = y2[f][r];   // cols identical
  }
  if (wv > 0) {
    int pi = wv - 1;
#pragma unroll
    for (int f = 0; f < 4; ++f)
#pragma unroll
      for (int r = 0; r < 4; ++r) {
        int lr = f * 16 + quad * 4 + r;
        smY[pi][lr][l16] = ya[f][r];
        smY[pi][lr][16 + l16] = yh[f][r];
      }
  }
  __syncthreads();
  if (wv == 0) {
#pragma unroll
    for (int f = 0; f < 4; ++f)
#pragma unroll
      for (int r = 0; r < 4; ++r) {
        int lr = f * 16 + quad * 4 + r;
        float a0 = ya[f][r] + smY[0][lr][l16] + smY[1][lr][l16] + smY[2][lr][l16];
        float a1 = yh[f][r] + smY[0][lr][16 + l16] + smY[1][lr][16 + l16] + smY[2][lr][16 + l16];
        float L = smL[0][lr] + smL[1][lr] + smL[2][lr] + smL[3][lr];
        float inv = 1.f / L;
        size_t rw = (size_t)bz * HW + qrow0 + lr;
        Y[rw * C2 + l16] = a0 * inv;
        Y[rw * C2 + 16 + l16] = a1 * inv;
      }
  }
}

// ---------------------------------------------------------------------------
// Kernel 3: output conv (32->64) + bias + residual — EXACT R4 version
// (R21's LDS-staged Y read regressed ~4 µs -> reverted). cog split x8,
// 2048 blocks = 8 blocks/CU; Y re-reads stay L2-resident.
// ---------------------------------------------------------------------------
__global__ __launch_bounds__(256) void conv_out_kern(
    const float* __restrict__ Y, const float* __restrict__ x,
    const float* __restrict__ w, const float* __restrict__ bias,
    float* __restrict__ out) {
  int p = blockIdx.x * 256 + threadIdx.x;
  int cog = blockIdx.y, bz = blockIdx.z;    // cog 0..7 -> channels cog*8..+7
  const float* xb = x + (size_t)bz * Cin * HW + p;
  float xr[8];
#pragma unroll
  for (int i = 0; i < 8; ++i)               // residual loads in flight
    xr[i] = xb[(size_t)(cog * 8 + i) * HW];
  float y[C2];
  const float4* yp4 = (const float4*)(Y + ((size_t)bz * HW + p) * C2);
#pragma unroll
  for (int i = 0; i < 8; ++i) {
    float4 t = yp4[i];
    y[4 * i] = t.x; y[4 * i + 1] = t.y; y[4 * i + 2] = t.z; y[4 * i + 3] = t.w;
  }
  float* ob = out + (size_t)bz * Cin * HW + p;
#pragma unroll
  for (int i = 0; i < 8; ++i) {
    int co = cog * 8 + i;
    float s = bias[co];
#pragma unroll
    for (int o = 0; o < C2; ++o) s = fmaf(w[co * C2 + o], y[o], s);  // s_load
    ob[(size_t)co * HW] = s + xr[i];
  }
}

// ---------------------------------------------------------------------------
extern "C" void kernel_launch(void* const* d_in, const int* in_sizes, int n_in,
                              void* d_out, int out_size, void* d_ws, size_t ws_size,
                              hipStream_t stream) {
  const float* x       = (const float*)d_in[0];
  const float* w_theta = (const float*)d_in[1];
  const float* b_theta = (const float*)d_in[2];
  const float* w_phi   = (const float*)d_in[3];
  const float* b_phi   = (const float*)d_in[4];
  const float* w_g     = (const float*)d_in[5];
  const float* b_g     = (const float*)d_in[6];
  const float* w_out   = (const float*)d_in[7];
  const float* b_out   = (const float*)d_in[8];
  float* out = (float*)d_out;

  float* Yws = (float*)d_ws;                                   // 8 MB fp32
  unsigned short* Qb = (unsigned short*)(Yws + (size_t)4 * HW * C2);
  unsigned short* Kb = Qb + (size_t)4 * HW * C2;
  unsigned short* Vt = Kb + (size_t)4 * HW4 * C2;
  float* wAll = (float*)(Vt + (size_t)4 * HW4 * C2);           // 6144 f
  float* bAll = wAll + 6144;                                   // 96 f

  repack_w_kern<<<25, 256, 0, stream>>>(w_theta, b_theta, w_phi, b_phi,
                                        w_g, b_g, wAll, bAll);
  conv_qkv_kern<<<dim3(64, 4, 4), 256, 0, stream>>>(x, wAll, bAll, Qb, Kb, Vt);
  attn_mfma_kern<<<dim3(HW / 64, 4), 256, 0, stream>>>(Qb, Kb, Vt, Yws);
  conv_out_kern<<<dim3(64, 8, 4), 256, 0, stream>>>(Yws, x, w_out, b_out, out);
}

// Round 10
// 152.204 us; speedup vs baseline: 1.1608x; 1.0582x over previous
//
#include <hip/hip_runtime.h>

#define HW    16384   // 128*128
#define Wh    128
#define Cin   64
#define C2    32
#define HW4   4096    // 64*64

typedef short short8 __attribute__((ext_vector_type(8)));     // 8 bf16 = 4 VGPRs
typedef float float4v __attribute__((ext_vector_type(4)));
typedef unsigned uint4v __attribute__((ext_vector_type(4)));

#define LOG2E 1.44269504f
#define OFFE  43.2808512f   // 30*log2(e): exp(s-30) == exp2(s*log2e - OFFE)

__device__ __forceinline__ unsigned pack2bf16(float lo, float hi) {
  unsigned ul = __builtin_bit_cast(unsigned, lo);
  unsigned uh = __builtin_bit_cast(unsigned, hi);
  ul = (ul + 0x7fffu + ((ul >> 16) & 1u)) >> 16;
  uh = (uh + 0x7fffu + ((uh >> 16) & 1u)) & 0xffff0000u;
  return ul | uh;
}
__device__ __forceinline__ unsigned short f2bf(float f) {
  unsigned u = __builtin_bit_cast(unsigned, f);
  return (unsigned short)((u + 0x7fffu + ((u >> 16) & 1u)) >> 16);
}
// RTZ-truncate two fp32 to bf16, lo in [15:0], hi in [31:16]
__device__ __forceinline__ unsigned packtrunc(float lo, float hi) {
  return __builtin_amdgcn_perm(__builtin_bit_cast(unsigned, hi),
                               __builtin_bit_cast(unsigned, lo), 0x07060302u);
}

// ---------------------------------------------------------------------------
// Kernel 0: weight repack. wAll[og][c][24] = {theta(8, x log2e), phi(8), g(8)}
// ---------------------------------------------------------------------------
__global__ __launch_bounds__(256) void repack_w_kern(
    const float* __restrict__ wt, const float* __restrict__ bt,
    const float* __restrict__ wp, const float* __restrict__ bp,
    const float* __restrict__ wg, const float* __restrict__ bg,
    float* __restrict__ wAll, float* __restrict__ bAll) {
  int idx = blockIdx.x * 256 + threadIdx.x;
  if (idx < 6144) {
    int og = idx / 1536, rem = idx % 1536;
    int c = rem / 24, j = rem % 24;
    int o = og * 8 + (j & 7);
    float v;
    if (j < 8)       v = wt[o * Cin + c] * LOG2E;
    else if (j < 16) v = wp[o * Cin + c];
    else             v = wg[o * Cin + c];
    wAll[idx] = v;
  } else if (idx < 6240) {
    int i2 = idx - 6144;
    int og = i2 / 24, j = i2 % 24;
    int o = og * 8 + (j & 7);
    bAll[i2] = (j < 8) ? bt[o] * LOG2E : (j < 16 ? bp[o] : bg[o]);
  }
}

// ---------------------------------------------------------------------------
// Kernel 1: FUSED theta+phi+g conv (+2x2 maxpool) — R0 form; ONLY the V
// store addressing changed (tile-major layout, see attn R24 note).
// Vt[bz][tile][ch][key_in_tile], tile = global_key >> 5. Same bf16 values.
// ---------------------------------------------------------------------------
__global__ __launch_bounds__(256) void conv_qkv_kern(
    const float* __restrict__ x, const float* __restrict__ wAll,
    const float* __restrict__ bAll, unsigned short* __restrict__ Q,
    unsigned short* __restrict__ K, unsigned short* __restrict__ Vt) {
  __shared__ float smX[2][8][256];               // 16 KB, double-buffered
  __shared__ unsigned short smV[8][64];          // 1 KB
  int tid = threadIdx.x;
  int og = blockIdx.y, bz = blockIdx.z;
  int pxbase = blockIdx.x * 2 * Wh;              // full-res rows 2i, 2i+1
  int jloc = tid >> 2;                           // pooled col 0..63
  int rpar = (tid >> 1) & 1, cpar = tid & 1;
  int myPx = rpar * Wh + 2 * jloc + cpar;        // local pixel 0..255
  const float* xb = x + (size_t)bz * Cin * HW + pxbase;
  const float* wc = wAll + og * 1536;            // uniform -> s_load
  const float* bb = bAll + og * 24;

  // stage chunk: 512 float4 = 256 threads x 2; ch = f>>6, p4 = f&63
  auto stage = [&](int cb8, int buf) {
#pragma unroll
    for (int u = 0; u < 2; ++u) {
      int f = u * 256 + tid;
      int ch = f >> 6, p4 = f & 63;
      *(float4*)&smX[buf][ch][p4 * 4] =
          *(const float4*)(xb + (size_t)(cb8 * 8 + ch) * HW + p4 * 4);
    }
  };

  float acc[24];
#pragma unroll
  for (int k = 0; k < 24; ++k) acc[k] = bb[k];

  stage(0, 0);
  __syncthreads();
  for (int cb8 = 0; cb8 < 8; ++cb8) {
    if (cb8 < 7) stage(cb8 + 1, (cb8 + 1) & 1);  // loads fly over compute
    float xv[8];
#pragma unroll
    for (int u = 0; u < 8; ++u) xv[u] = smX[cb8 & 1][u][myPx];
#pragma unroll
    for (int u = 0; u < 8; ++u) {
#pragma unroll
      for (int k = 0; k < 24; ++k)
        acc[k] = fmaf(wc[(cb8 * 8 + u) * 24 + k], xv[u], acc[k]);
    }
    __syncthreads();                             // staged buf ready for next
  }

  int pp = blockIdx.x * 64 + jloc;               // global pooled pixel
  int p = pxbase + myPx;                         // global full-res pixel
  // theta -> Q
  {
    uint4 up;
    up.x = pack2bf16(acc[0], acc[1]); up.y = pack2bf16(acc[2], acc[3]);
    up.z = pack2bf16(acc[4], acc[5]); up.w = pack2bf16(acc[6], acc[7]);
    *(uint4*)(Q + ((size_t)bz * HW + p) * C2 + og * 8) = up;
  }
  // 2x2 maxpool across lane-mates {4j..4j+3}
  float aP[8], aG[8];
#pragma unroll
  for (int o = 0; o < 8; ++o) {
    float vp = acc[8 + o], vg = acc[16 + o];
    vp = fmaxf(vp, __shfl_xor(vp, 1)); vp = fmaxf(vp, __shfl_xor(vp, 2));
    vg = fmaxf(vg, __shfl_xor(vg, 1)); vg = fmaxf(vg, __shfl_xor(vg, 2));
    aP[o] = vp; aG[o] = vg;
  }
  if ((tid & 3) == 0) {
    int loc = pp & 31, tile = pp >> 5;
    int prow = ((loc & 4) << 2) + ((loc >> 3) << 2) + (loc & 3);   // S^T perm
    uint4 up;
    up.x = pack2bf16(aP[0], aP[1]); up.y = pack2bf16(aP[2], aP[3]);
    up.z = pack2bf16(aP[4], aP[5]); up.w = pack2bf16(aP[6], aP[7]);
    *(uint4*)(K + ((size_t)bz * HW4 + tile * 32 + prow) * C2 + og * 8) = up;
#pragma unroll
    for (int o = 0; o < 8; ++o) smV[o][tid >> 2] = f2bf(aG[o]);
  }
  __syncthreads();
  // V store, TILE-MAJOR: Vt[bz][tile][ch][kin]. thread t -> ch t>>5,
  // keys 2*(t&31), 2*(t&31)+1 (one dword, same tile). Wave = two 128 B
  // segments -> coalesced.
  {
    int ch = tid >> 5, idx = tid & 31;
    unsigned v = ((unsigned*)smV)[ch * 32 + idx];
    int tile = blockIdx.x * 2 + (idx >> 4);      // key64 = 2*idx
    int kin = (2 * idx) & 31;
    *(unsigned*)(Vt + (size_t)bz * C2 * HW4 + (size_t)tile * (C2 * 32) +
                 (size_t)(og * 8 + ch) * 32 + kin) = v;
  }
}

// ---------------------------------------------------------------------------
// Kernel 2: MFMA flash attention — R24: TILE-MAJOR V => ALL LOADS CONTIGUOUS.
// Ledger model (fits R0/R3/R4/R8/R9): attn wall tracks VMEM load-instr
// count per SIMD, ~280 cyc/load service. Old Vt[ch][key] made va/vh
// 16-segment scatters (lane l16 at 8 KB stride: 16 distinct 64 B line
// fragments per instr, half-line used, 128 KB span) — half the kernel's
// loads. New layout: V tile = 2 KB contiguous; va = 1 KB contiguous
// wave-load, vh adjacent. K already tile-contiguous. Loop body otherwise
// the proven R0 depth-first form (6 scheduling probes: leave it alone).
// Occupancy door confirmed shut (R2 spill at cap 64; R3 load-doubling).
// Bitwise-identical: same values, new addresses only.
// ---------------------------------------------------------------------------
__global__ __launch_bounds__(256, 4) void attn_mfma_kern(
    const unsigned short* __restrict__ Qb, const unsigned short* __restrict__ Kb,
    const unsigned short* __restrict__ Vt, float* __restrict__ Y) {
  __shared__ float smY[3][64][33];   // 25.3 KB
  __shared__ float smL[4][64];       // 1 KB
  int lane = threadIdx.x & 63;
  int wv = threadIdx.x >> 6;
  int quad = lane >> 4, l16 = lane & 15;
  int bz = blockIdx.y;
  int qrow0 = blockIdx.x * 64;

  short8 qf[4];
#pragma unroll
  for (int f = 0; f < 4; ++f)
    qf[f] = *(const short8*)(Qb + ((size_t)bz * HW + qrow0 + f * 16 + l16) * C2 + quad * 8);
  const unsigned short* kb = Kb + ((size_t)bz * HW4 + wv * 1024) * C2;
  // wave wv's quarter = tiles wv*32 .. wv*32+31; one tile = C2*32 = 1024 shorts
  const unsigned short* vb = Vt + (size_t)bz * C2 * HW4 + (size_t)(wv * 32) * 1024;

  short8 ones;
#pragma unroll
  for (int i = 0; i < 8; ++i) ones[i] = (short)0x3F80;  // bf16 1.0

  float4v z = {0.f, 0.f, 0.f, 0.f};
  float4v ya[4] = {z, z, z, z};   // y cols l16 (ch 0..15)
  float4v yh[4] = {z, z, z, z};   // y cols 16+l16
  float4v y2[4] = {z, z, z, z};   // row sums l (ones-MFMA)
  float4v moff = {-OFFE, -OFFE, -OFFE, -OFFE};

  for (int t = 0; t < 32; ++t) {
    const unsigned short* kt = kb + (size_t)t * 32 * C2;
    const unsigned short* vt = vb + (size_t)t * 1024;
    short8 ka = *(const short8*)(kt + (size_t)l16 * C2 + quad * 8);
    short8 kh = *(const short8*)(kt + (size_t)(16 + l16) * C2 + quad * 8);
    short8 va = *(const short8*)(vt + l16 * 32 + quad * 8);          // 1 KB contig
    short8 vh = *(const short8*)(vt + (16 + l16) * 32 + quad * 8);   // next 1 KB
#pragma unroll
    for (int f = 0; f < 4; ++f) {
      float4v sa = __builtin_amdgcn_mfma_f32_16x16x32_bf16(ka, qf[f], moff, 0, 0, 0);
      float4v sh = __builtin_amdgcn_mfma_f32_16x16x32_bf16(kh, qf[f], moff, 0, 0, 0);
      float e0 = __builtin_amdgcn_exp2f(sa[0]), e1 = __builtin_amdgcn_exp2f(sa[1]);
      float e2 = __builtin_amdgcn_exp2f(sa[2]), e3 = __builtin_amdgcn_exp2f(sa[3]);
      float g0 = __builtin_amdgcn_exp2f(sh[0]), g1 = __builtin_amdgcn_exp2f(sh[1]);
      float g2 = __builtin_amdgcn_exp2f(sh[2]), g3 = __builtin_amdgcn_exp2f(sh[3]);
      uint4v d = {packtrunc(e0, e1), packtrunc(e2, e3),
                  packtrunc(g0, g1), packtrunc(g2, g3)};
      short8 pf = __builtin_bit_cast(short8, d);
      ya[f] = __builtin_amdgcn_mfma_f32_16x16x32_bf16(pf, va,   ya[f], 0, 0, 0);
      yh[f] = __builtin_amdgcn_mfma_f32_16x16x32_bf16(pf, vh,   yh[f], 0, 0, 0);
      y2[f] = __builtin_amdgcn_mfma_f32_16x16x32_bf16(pf, ones, y2[f], 0, 0, 0);
    }
  }

  // merge the 4 key quarters (R0 epilogue, unchanged)
  if (l16 == 0) {
#pragma unroll
    for (int f = 0; f < 4; ++f)
#pragma unroll
      for (int r = 0; r < 4; ++r)
        smL[wv][f * 16 + quad * 4 + r] = y2[f][r];   // cols identical
  }
  if (wv > 0) {
    int pi = wv - 1;
#pragma unroll
    for (int f = 0; f < 4; ++f)
#pragma unroll
      for (int r = 0; r < 4; ++r) {
        int lr = f * 16 + quad * 4 + r;
        smY[pi][lr][l16] = ya[f][r];
        smY[pi][lr][16 + l16] = yh[f][r];
      }
  }
  __syncthreads();
  if (wv == 0) {
#pragma unroll
    for (int f = 0; f < 4; ++f)
#pragma unroll
      for (int r = 0; r < 4; ++r) {
        int lr = f * 16 + quad * 4 + r;
        float a0 = ya[f][r] + smY[0][lr][l16] + smY[1][lr][l16] + smY[2][lr][l16];
        float a1 = yh[f][r] + smY[0][lr][16 + l16] + smY[1][lr][16 + l16] + smY[2][lr][16 + l16];
        float L = smL[0][lr] + smL[1][lr] + smL[2][lr] + smL[3][lr];
        float inv = 1.f / L;
        size_t rw = (size_t)bz * HW + qrow0 + lr;
        Y[rw * C2 + l16] = a0 * inv;
        Y[rw * C2 + 16 + l16] = a1 * inv;
      }
  }
}

// ---------------------------------------------------------------------------
// Kernel 3: output conv (32->64) + bias + residual — EXACT R4 version
// (best measured; R21 LDS staging regressed). cog split x8, 2048 blocks.
// ---------------------------------------------------------------------------
__global__ __launch_bounds__(256) void conv_out_kern(
    const float* __restrict__ Y, const float* __restrict__ x,
    const float* __restrict__ w, const float* __restrict__ bias,
    float* __restrict__ out) {
  int p = blockIdx.x * 256 + threadIdx.x;
  int cog = blockIdx.y, bz = blockIdx.z;    // cog 0..7 -> channels cog*8..+7
  const float* xb = x + (size_t)bz * Cin * HW + p;
  float xr[8];
#pragma unroll
  for (int i = 0; i < 8; ++i)               // residual loads in flight
    xr[i] = xb[(size_t)(cog * 8 + i) * HW];
  float y[C2];
  const float4* yp4 = (const float4*)(Y + ((size_t)bz * HW + p) * C2);
#pragma unroll
  for (int i = 0; i < 8; ++i) {
    float4 t = yp4[i];
    y[4 * i] = t.x; y[4 * i + 1] = t.y; y[4 * i + 2] = t.z; y[4 * i + 3] = t.w;
  }
  float* ob = out + (size_t)bz * Cin * HW + p;
#pragma unroll
  for (int i = 0; i < 8; ++i) {
    int co = cog * 8 + i;
    float s = bias[co];
#pragma unroll
    for (int o = 0; o < C2; ++o) s = fmaf(w[co * C2 + o], y[o], s);  // s_load
    ob[(size_t)co * HW] = s + xr[i];
  }
}

// ---------------------------------------------------------------------------
extern "C" void kernel_launch(void* const* d_in, const int* in_sizes, int n_in,
                              void* d_out, int out_size, void* d_ws, size_t ws_size,
                              hipStream_t stream) {
  const float* x       = (const float*)d_in[0];
  const float* w_theta = (const float*)d_in[1];
  const float* b_theta = (const float*)d_in[2];
  const float* w_phi   = (const float*)d_in[3];
  const float* b_phi   = (const float*)d_in[4];
  const float* w_g     = (const float*)d_in[5];
  const float* b_g     = (const float*)d_in[6];
  const float* w_out   = (const float*)d_in[7];
  const float* b_out   = (const float*)d_in[8];
  float* out = (float*)d_out;

  float* Yws = (float*)d_ws;                                   // 8 MB fp32
  unsigned short* Qb = (unsigned short*)(Yws + (size_t)4 * HW * C2);
  unsigned short* Kb = Qb + (size_t)4 * HW * C2;
  unsigned short* Vt = Kb + (size_t)4 * HW4 * C2;
  float* wAll = (float*)(Vt + (size_t)4 * HW4 * C2);           // 6144 f
  float* bAll = wAll + 6144;                                   // 96 f

  repack_w_kern<<<25, 256, 0, stream>>>(w_theta, b_theta, w_phi, b_phi,
                                        w_g, b_g, wAll, bAll);
  conv_qkv_kern<<<dim3(64, 4, 4), 256, 0, stream>>>(x, wAll, bAll, Qb, Kb, Vt);
  attn_mfma_kern<<<dim3(HW / 64, 4), 256, 0, stream>>>(Qb, Kb, Vt, Yws);
  conv_out_kern<<<dim3(64, 8, 4), 256, 0, stream>>>(Yws, x, w_out, b_out, out);
}